// Round 3
// baseline (223.405 us; speedup 1.0000x reference)
//
#include <hip/hip_runtime.h>
#include <stdint.h>

// CapsuleLayer dynamic routing, fused. Round 3:
//  - BT=4 batches/block (halves W traffic vs BT=2)
//  - priors stored bf16-packed (72 VGPR) -> room for 2-deep load pipeline
//  - XCD-grouped swizzle: blocks sharing W[c] land on the same XCD's L2
//
// x:  [B=256, N=1152, CIN=8] fp32 | W: [10, 1152, 8, 16] fp32
// out:[10, B, 1, 1, 16] fp32

constexpr int NCAPS  = 10;
constexpr int BATCH  = 256;
constexpr int NROUTE = 1152;
constexpr int CIN    = 8;
constexpr int COUT   = 16;
constexpr int T      = 512;                      // 8 waves
constexpr int NWAVES = T / 64;
constexpr int BT     = 4;                        // batches per block
constexpr int NSTEP  = NROUTE / (NWAVES * 16);   // 9
constexpr int BG     = BATCH / BT;               // 64
constexpr int GRID   = NCAPS * BG;               // 640
constexpr int CPX    = GRID / 8;                 // 80 blocks per XCD

struct SMem {
    float red16[NWAVES][BT][COUT];
    float redS[NWAVES][BT];
};

__device__ inline uint32_t bf16rne(float f) {
    uint32_t u = __float_as_uint(f);
    return (u + 0x7fffu + ((u >> 16) & 1u)) >> 16;
}
__device__ inline uint32_t packbf(float a, float b) {
    return (bf16rne(a) << 16) | bf16rne(b);
}
__device__ inline float2 unpk(uint32_t u) {
    return make_float2(__uint_as_float(u & 0xffff0000u),
                       __uint_as_float(u << 16));
}
__device__ inline float fcomp(const float4& v, int j) {   // j compile-time
    return j == 0 ? v.x : j == 1 ? v.y : j == 2 ? v.z : v.w;
}

// Reduce part[b][j] over nn-groups (shfl 4..32) then across waves (LDS).
__device__ inline void blk_red16(SMem& sm, float part[BT][4], float sout[BT][4],
                                 int lane, int wid, int oq) {
#pragma unroll
    for (int b = 0; b < BT; ++b)
#pragma unroll
        for (int j = 0; j < 4; ++j) {
            float t = part[b][j];
#pragma unroll
            for (int off = 4; off < 64; off <<= 1) t += __shfl_xor(t, off, 64);
            part[b][j] = t;
        }
    __syncthreads();
    if (lane < 4) {
#pragma unroll
        for (int b = 0; b < BT; ++b)
#pragma unroll
            for (int j = 0; j < 4; ++j) sm.red16[wid][b][lane * 4 + j] = part[b][j];
    }
    __syncthreads();
#pragma unroll
    for (int b = 0; b < BT; ++b)
#pragma unroll
        for (int j = 0; j < 4; ++j) {
            float acc = sm.red16[0][b][oq * 4 + j];
#pragma unroll
            for (int w = 1; w < NWAVES; ++w) acc += sm.red16[w][b][oq * 4 + j];
            sout[b][j] = acc;
        }
}

#define LOADSTEP(KK, BUF) do {                                                   \
    const int n_ = (KK) * 128 + nbase;                                           \
    const float4* wp_ = reinterpret_cast<const float4*>(Wc + (size_t)n_ * 128) + oq; \
    _Pragma("unroll")                                                            \
    for (int i_ = 0; i_ < 8; ++i_) wreg[BUF][i_] = wp_[i_ * 4];                  \
    _Pragma("unroll")                                                            \
    for (int b_ = 0; b_ < BT; ++b_) {                                            \
        const float4* xp_ = reinterpret_cast<const float4*>(                     \
            xbase + (size_t)b_ * (NROUTE * CIN) + (size_t)n_ * CIN);             \
        xreg[BUF][b_ * 2 + 0] = xp_[0];                                          \
        xreg[BUF][b_ * 2 + 1] = xp_[1];                                          \
    }                                                                            \
} while (0)

__global__ __launch_bounds__(T, 1)
void capsule_routing_kernel(const float* __restrict__ x,
                            const float* __restrict__ Wt,
                            float* __restrict__ out) {
    __shared__ SMem sm;
    const int phys    = blockIdx.x;
    const int logical = (phys & 7) * CPX + (phys >> 3);   // XCD-grouped, c-major
    const int c  = logical / BG;
    const int b0 = (logical % BG) * BT;
    const int tid  = threadIdx.x;
    const int lane = tid & 63;
    const int wid  = tid >> 6;
    const int nn   = lane >> 2;
    const int oq   = lane & 3;
    const int nbase = wid * 16 + nn;

    const float* Wc    = Wt + (size_t)c * NROUTE * (CIN * COUT);
    const float* xbase = x + (size_t)b0 * NROUTE * CIN;

    // ---- priors: 2-deep register pipeline --------------------------------
    uint32_t pk[BT][NSTEP][2];
    float4 wreg[2][8];
    float4 xreg[2][8];

    LOADSTEP(0, 0);
#pragma unroll
    for (int k = 0; k < NSTEP; ++k) {
        const int cur = k & 1;
        if (k + 1 < NSTEP) {
            if (cur == 0) { LOADSTEP(k + 1, 1); } else { LOADSTEP(k + 1, 0); }
        }
        float a[BT][4];
#pragma unroll
        for (int b = 0; b < BT; ++b)
#pragma unroll
            for (int j = 0; j < 4; ++j) a[b][j] = 0.f;
#pragma unroll
        for (int i = 0; i < 8; ++i) {
            float4 w4 = wreg[cur][i];
#pragma unroll
            for (int b = 0; b < BT; ++b) {
                float xi = fcomp(xreg[cur][b * 2 + (i >> 2)], i & 3);
                a[b][0] = fmaf(xi, w4.x, a[b][0]);
                a[b][1] = fmaf(xi, w4.y, a[b][1]);
                a[b][2] = fmaf(xi, w4.z, a[b][2]);
                a[b][3] = fmaf(xi, w4.w, a[b][3]);
            }
        }
#pragma unroll
        for (int b = 0; b < BT; ++b) {
            pk[b][k][0] = packbf(a[b][0], a[b][1]);
            pk[b][k][1] = packbf(a[b][2], a[b][3]);
        }
    }

    float part[BT][4], s[BT][4], v[BT][4];
    float bl[BT][NSTEP], e[BT][NSTEP];

    // ---- iteration 0: uniform probs --------------------------------------
#pragma unroll
    for (int b = 0; b < BT; ++b) {
        float a0 = 0, a1 = 0, a2 = 0, a3 = 0;
#pragma unroll
        for (int k = 0; k < NSTEP; ++k) {
            float2 u0 = unpk(pk[b][k][0]);
            float2 u1 = unpk(pk[b][k][1]);
            a0 += u0.x; a1 += u0.y; a2 += u1.x; a3 += u1.y;
        }
        part[b][0] = a0; part[b][1] = a1; part[b][2] = a2; part[b][3] = a3;
    }
    blk_red16(sm, part, s, lane, wid, oq);
#pragma unroll
    for (int b = 0; b < BT; ++b) {
        float sn = 0.f;
#pragma unroll
        for (int j = 0; j < 4; ++j) { s[b][j] *= (1.0f / NROUTE); sn += s[b][j] * s[b][j]; }
        sn += __shfl_xor(sn, 1, 64);
        sn += __shfl_xor(sn, 2, 64);
        float scale = sn / ((1.f + sn) * sqrtf(sn));
#pragma unroll
        for (int j = 0; j < 4; ++j) v[b][j] = s[b][j] * scale;
    }
#pragma unroll
    for (int b = 0; b < BT; ++b)
#pragma unroll
        for (int k = 0; k < NSTEP; ++k) {
            float2 u0 = unpk(pk[b][k][0]);
            float2 u1 = unpk(pk[b][k][1]);
            float d = u0.x * v[b][0] + u0.y * v[b][1] + u1.x * v[b][2] + u1.y * v[b][3];
            d += __shfl_xor(d, 1, 64);
            d += __shfl_xor(d, 2, 64);
            bl[b][k] = d;
        }

    // ---- iterations 1, 2 --------------------------------------------------
#pragma unroll
    for (int it = 1; it < 3; ++it) {
        float m[BT];
#pragma unroll
        for (int b = 0; b < BT; ++b) {
            float mm = bl[b][0];
#pragma unroll
            for (int k = 1; k < NSTEP; ++k) mm = fmaxf(mm, bl[b][k]);
#pragma unroll
            for (int off = 1; off < 64; off <<= 1) mm = fmaxf(mm, __shfl_xor(mm, off, 64));
            m[b] = mm;
        }
        __syncthreads();
        if (lane == 0) {
#pragma unroll
            for (int b = 0; b < BT; ++b) sm.redS[wid][b] = m[b];
        }
        __syncthreads();
#pragma unroll
        for (int b = 0; b < BT; ++b) {
            float mm = sm.redS[0][b];
#pragma unroll
            for (int w = 1; w < NWAVES; ++w) mm = fmaxf(mm, sm.redS[w][b]);
            m[b] = mm;
        }

        float es[BT];
#pragma unroll
        for (int b = 0; b < BT; ++b) {
            float a = 0.f;
#pragma unroll
            for (int k = 0; k < NSTEP; ++k) { e[b][k] = __expf(bl[b][k] - m[b]); a += e[b][k]; }
#pragma unroll
            for (int off = 1; off < 64; off <<= 1) a += __shfl_xor(a, off, 64);
            es[b] = a;
        }
        __syncthreads();
        if (lane == 0) {
#pragma unroll
            for (int b = 0; b < BT; ++b) sm.redS[wid][b] = es[b];
        }
        __syncthreads();
        float invZ[BT];
#pragma unroll
        for (int b = 0; b < BT; ++b) {
            float a = sm.redS[0][b];
#pragma unroll
            for (int w = 1; w < NWAVES; ++w) a += sm.redS[w][b];
            invZ[b] = 4.0f / a;            // each n counted 4x across quad
        }

#pragma unroll
        for (int b = 0; b < BT; ++b) {
            float a0 = 0, a1 = 0, a2 = 0, a3 = 0;
#pragma unroll
            for (int k = 0; k < NSTEP; ++k) {
                float2 u0 = unpk(pk[b][k][0]);
                float2 u1 = unpk(pk[b][k][1]);
                float ek = e[b][k];
                a0 = fmaf(ek, u0.x, a0); a1 = fmaf(ek, u0.y, a1);
                a2 = fmaf(ek, u1.x, a2); a3 = fmaf(ek, u1.y, a3);
            }
            part[b][0] = a0; part[b][1] = a1; part[b][2] = a2; part[b][3] = a3;
        }
        blk_red16(sm, part, s, lane, wid, oq);
#pragma unroll
        for (int b = 0; b < BT; ++b) {
            float sn = 0.f;
#pragma unroll
            for (int j = 0; j < 4; ++j) { s[b][j] *= invZ[b]; sn += s[b][j] * s[b][j]; }
            sn += __shfl_xor(sn, 1, 64);
            sn += __shfl_xor(sn, 2, 64);
            float scale = sn / ((1.f + sn) * sqrtf(sn));
#pragma unroll
            for (int j = 0; j < 4; ++j) v[b][j] = s[b][j] * scale;
        }

        if (it < 2) {
#pragma unroll
            for (int b = 0; b < BT; ++b)
#pragma unroll
                for (int k = 0; k < NSTEP; ++k) {
                    float2 u0 = unpk(pk[b][k][0]);
                    float2 u1 = unpk(pk[b][k][1]);
                    float d = u0.x * v[b][0] + u0.y * v[b][1] + u1.x * v[b][2] + u1.y * v[b][3];
                    d += __shfl_xor(d, 1, 64);
                    d += __shfl_xor(d, 2, 64);
                    bl[b][k] += d;
                }
        }
    }

    // ---- write out[c, b0..b0+3, 0, 0, :] ---------------------------------
    if (tid < 4) {                         // wave 0, nn=0, lane==oq==tid
#pragma unroll
        for (int b = 0; b < BT; ++b) {
            float4 o = make_float4(v[b][0], v[b][1], v[b][2], v[b][3]);
            *reinterpret_cast<float4*>(
                out + ((size_t)(c * BATCH + b0 + b) * COUT) + tid * 4) = o;
        }
    }
}

extern "C" void kernel_launch(void* const* d_in, const int* in_sizes, int n_in,
                              void* d_out, int out_size, void* d_ws, size_t ws_size,
                              hipStream_t stream) {
    const float* x  = (const float*)d_in[0];
    const float* Wt = (const float*)d_in[1];
    float* out = (float*)d_out;
    capsule_routing_kernel<<<dim3(GRID), dim3(T), 0, stream>>>(x, Wt, out);
}

// Round 4
// 198.775 us; speedup vs baseline: 1.1239x; 1.1239x over previous
//
#include <hip/hip_runtime.h>
#include <stdint.h>

// CapsuleLayer dynamic routing, fused. Round 4:
//  - BT=4, bf16-packed priors, XCD-grouped c-major swizzle (as round 3)
//  - register diet: no e[] array (fused exp/Z/part pass), bl not live in
//    prior phase, launch_bounds(512,2) -> VGPR cap 256, no spill
//
// x:  [B=256, N=1152, CIN=8] fp32 | W: [10, 1152, 8, 16] fp32
// out:[10, B, 1, 1, 16] fp32

constexpr int NCAPS  = 10;
constexpr int BATCH  = 256;
constexpr int NROUTE = 1152;
constexpr int CIN    = 8;
constexpr int COUT   = 16;
constexpr int T      = 512;                      // 8 waves
constexpr int NWAVES = T / 64;
constexpr int BT     = 4;                        // batches per block
constexpr int NSTEP  = NROUTE / (NWAVES * 16);   // 9
constexpr int BG     = BATCH / BT;               // 64
constexpr int GRID   = NCAPS * BG;               // 640 (640%8==0: bijective swizzle)
constexpr int CPX    = GRID / 8;                 // 80 blocks per XCD

struct SMem {
    float red16[NWAVES][BT][COUT];
    float sred[NWAVES][BT];
};

__device__ inline uint32_t bf16rne(float f) {
    uint32_t u = __float_as_uint(f);
    return (u + 0x7fffu + ((u >> 16) & 1u)) >> 16;
}
__device__ inline uint32_t packbf(float a, float b) {
    return (bf16rne(a) << 16) | bf16rne(b);
}
__device__ inline float2 unpk(uint32_t u) {
    return make_float2(__uint_as_float(u & 0xffff0000u),
                       __uint_as_float(u << 16));
}
__device__ inline float fcomp(const float4& v, int j) {   // j compile-time
    return j == 0 ? v.x : j == 1 ? v.y : j == 2 ? v.z : v.w;
}

#define LOADW(KK, BUF) do {                                                      \
    const int n_ = (KK) * 128 + nbase;                                           \
    const float4* wp_ = reinterpret_cast<const float4*>(Wc + (size_t)n_ * 128) + oq; \
    _Pragma("unroll")                                                            \
    for (int i_ = 0; i_ < 8; ++i_) wreg[BUF][i_] = wp_[i_ * 4];                  \
} while (0)

#define LOADX(KK, BUF) do {                                                      \
    const int n_ = (KK) * 128 + nbase;                                           \
    _Pragma("unroll")                                                            \
    for (int b_ = 0; b_ < BT; ++b_) {                                            \
        const float4* xp_ = reinterpret_cast<const float4*>(                     \
            xbase + (size_t)b_ * (NROUTE * CIN) + (size_t)n_ * CIN);             \
        xreg[BUF][b_ * 2 + 0] = xp_[0];                                          \
        xreg[BUF][b_ * 2 + 1] = xp_[1];                                          \
    }                                                                            \
} while (0)

__global__ __launch_bounds__(T, 2)
void capsule_routing_kernel(const float* __restrict__ x,
                            const float* __restrict__ Wt,
                            float* __restrict__ out) {
    __shared__ SMem sm;
    const int phys    = blockIdx.x;
    const int logical = (phys & 7) * CPX + (phys >> 3);   // XCD-grouped, c-major
    const int c  = logical / BG;
    const int b0 = (logical % BG) * BT;
    const int tid  = threadIdx.x;
    const int lane = tid & 63;
    const int wid  = tid >> 6;
    const int nn   = lane >> 2;
    const int oq   = lane & 3;
    const int nbase = wid * 16 + nn;

    const float* Wc    = Wt + (size_t)c * NROUTE * (CIN * COUT);
    const float* xbase = x + (size_t)b0 * NROUTE * CIN;

    // ---- priors: 2-deep register pipeline, bf16-packed storage -----------
    uint32_t pk[BT][NSTEP][2];
    float4 wreg[2][8];
    float4 xreg[2][8];

    LOADW(0, 0);
    LOADX(0, 0);
#pragma unroll
    for (int k = 0; k < NSTEP; ++k) {
        const int cur = k & 1;
        const int nxt = cur ^ 1;
        if (k + 1 < NSTEP) {
            if (nxt) { LOADW(k + 1, 1); LOADX(k + 1, 1); }
            else     { LOADW(k + 1, 0); LOADX(k + 1, 0); }
        }
#pragma unroll
        for (int b = 0; b < BT; ++b) {
            float a0 = 0.f, a1 = 0.f, a2 = 0.f, a3 = 0.f;
#pragma unroll
            for (int i = 0; i < 8; ++i) {
                float4 w4 = wreg[cur][i];
                float xi = fcomp(xreg[cur][b * 2 + (i >> 2)], i & 3);
                a0 = fmaf(xi, w4.x, a0);
                a1 = fmaf(xi, w4.y, a1);
                a2 = fmaf(xi, w4.z, a2);
                a3 = fmaf(xi, w4.w, a3);
            }
            pk[b][k][0] = packbf(a0, a1);
            pk[b][k][1] = packbf(a2, a3);
        }
    }

    float part[BT][4], s[BT][4], v[BT][4], bl[BT][NSTEP];

    // ---- iteration 0: probs uniform 1/N ----------------------------------
#pragma unroll
    for (int b = 0; b < BT; ++b) {
        float a0 = 0, a1 = 0, a2 = 0, a3 = 0;
#pragma unroll
        for (int k = 0; k < NSTEP; ++k) {
            float2 u0 = unpk(pk[b][k][0]);
            float2 u1 = unpk(pk[b][k][1]);
            a0 += u0.x; a1 += u0.y; a2 += u1.x; a3 += u1.y;
        }
        part[b][0] = a0; part[b][1] = a1; part[b][2] = a2; part[b][3] = a3;
    }
    // block reduce (n) for the 4 o's, keep oq split
#pragma unroll
    for (int b = 0; b < BT; ++b)
#pragma unroll
        for (int j = 0; j < 4; ++j) {
            float t = part[b][j];
#pragma unroll
            for (int off = 4; off < 64; off <<= 1) t += __shfl_xor(t, off, 64);
            part[b][j] = t;
        }
    __syncthreads();
    if (lane < 4) {
#pragma unroll
        for (int b = 0; b < BT; ++b)
#pragma unroll
            for (int j = 0; j < 4; ++j) sm.red16[wid][b][lane * 4 + j] = part[b][j];
    }
    __syncthreads();
#pragma unroll
    for (int b = 0; b < BT; ++b) {
        float sn = 0.f;
#pragma unroll
        for (int j = 0; j < 4; ++j) {
            float acc = sm.red16[0][b][oq * 4 + j];
#pragma unroll
            for (int w = 1; w < NWAVES; ++w) acc += sm.red16[w][b][oq * 4 + j];
            s[b][j] = acc * (1.0f / NROUTE);
            sn += s[b][j] * s[b][j];
        }
        sn += __shfl_xor(sn, 1, 64);
        sn += __shfl_xor(sn, 2, 64);
        float scale = sn / ((1.f + sn) * sqrtf(sn));
#pragma unroll
        for (int j = 0; j < 4; ++j) v[b][j] = s[b][j] * scale;
    }
#pragma unroll
    for (int b = 0; b < BT; ++b)
#pragma unroll
        for (int k = 0; k < NSTEP; ++k) {
            float2 u0 = unpk(pk[b][k][0]);
            float2 u1 = unpk(pk[b][k][1]);
            float d = u0.x * v[b][0] + u0.y * v[b][1] + u1.x * v[b][2] + u1.y * v[b][3];
            d += __shfl_xor(d, 1, 64);
            d += __shfl_xor(d, 2, 64);
            bl[b][k] = d;
        }

    // ---- iterations 1, 2 --------------------------------------------------
#pragma unroll
    for (int it = 1; it < 3; ++it) {
        // softmax max over n (oq duplicates harmless)
        float m[BT];
#pragma unroll
        for (int b = 0; b < BT; ++b) {
            float mm = bl[b][0];
#pragma unroll
            for (int k = 1; k < NSTEP; ++k) mm = fmaxf(mm, bl[b][k]);
#pragma unroll
            for (int off = 1; off < 64; off <<= 1) mm = fmaxf(mm, __shfl_xor(mm, off, 64));
            m[b] = mm;
        }
        __syncthreads();
        if (lane == 0) {
#pragma unroll
            for (int b = 0; b < BT; ++b) sm.sred[wid][b] = m[b];
        }
        __syncthreads();
#pragma unroll
        for (int b = 0; b < BT; ++b) {
            float mm = sm.sred[0][b];
#pragma unroll
            for (int w = 1; w < NWAVES; ++w) mm = fmaxf(mm, sm.sred[w][b]);
            m[b] = mm;
        }

        // fused pass: e = exp(bl-m) accumulated into Z and the 4 o-partials
        float es[BT];
#pragma unroll
        for (int b = 0; b < BT; ++b) {
            float ez = 0.f, a0 = 0, a1 = 0, a2 = 0, a3 = 0;
#pragma unroll
            for (int k = 0; k < NSTEP; ++k) {
                float ek = __expf(bl[b][k] - m[b]);
                ez += ek;
                float2 u0 = unpk(pk[b][k][0]);
                float2 u1 = unpk(pk[b][k][1]);
                a0 = fmaf(ek, u0.x, a0); a1 = fmaf(ek, u0.y, a1);
                a2 = fmaf(ek, u1.x, a2); a3 = fmaf(ek, u1.y, a3);
            }
            // parts: reduce over nn-groups/waves only (keep oq)
#pragma unroll
            for (int off = 4; off < 64; off <<= 1) {
                a0 += __shfl_xor(a0, off, 64);
                a1 += __shfl_xor(a1, off, 64);
                a2 += __shfl_xor(a2, off, 64);
                a3 += __shfl_xor(a3, off, 64);
            }
            part[b][0] = a0; part[b][1] = a1; part[b][2] = a2; part[b][3] = a3;
            // Z: full-wave reduce (each n counted 4x over oq -> invZ = 4/Z)
#pragma unroll
            for (int off = 1; off < 64; off <<= 1) ez += __shfl_xor(ez, off, 64);
            es[b] = ez;
        }
        __syncthreads();
        if (lane < 4) {
#pragma unroll
            for (int b = 0; b < BT; ++b) {
#pragma unroll
                for (int j = 0; j < 4; ++j) sm.red16[wid][b][lane * 4 + j] = part[b][j];
                if (lane == 0) sm.sred[wid][b] = es[b];
            }
        }
        __syncthreads();
#pragma unroll
        for (int b = 0; b < BT; ++b) {
            float z = sm.sred[0][b];
#pragma unroll
            for (int w = 1; w < NWAVES; ++w) z += sm.sred[w][b];
            float invZ = 4.0f / z;
            float sn = 0.f;
#pragma unroll
            for (int j = 0; j < 4; ++j) {
                float acc = sm.red16[0][b][oq * 4 + j];
#pragma unroll
                for (int w = 1; w < NWAVES; ++w) acc += sm.red16[w][b][oq * 4 + j];
                s[b][j] = acc * invZ;
                sn += s[b][j] * s[b][j];
            }
            sn += __shfl_xor(sn, 1, 64);
            sn += __shfl_xor(sn, 2, 64);
            float scale = sn / ((1.f + sn) * sqrtf(sn));
#pragma unroll
            for (int j = 0; j < 4; ++j) v[b][j] = s[b][j] * scale;
        }

        if (it < 2) {
#pragma unroll
            for (int b = 0; b < BT; ++b)
#pragma unroll
                for (int k = 0; k < NSTEP; ++k) {
                    float2 u0 = unpk(pk[b][k][0]);
                    float2 u1 = unpk(pk[b][k][1]);
                    float d = u0.x * v[b][0] + u0.y * v[b][1] + u1.x * v[b][2] + u1.y * v[b][3];
                    d += __shfl_xor(d, 1, 64);
                    d += __shfl_xor(d, 2, 64);
                    bl[b][k] += d;
                }
        }
    }

    // ---- write out[c, b0..b0+3, 0, 0, :] ---------------------------------
    if (tid < 4) {                         // wave 0, nn=0, lane==oq==tid
#pragma unroll
        for (int b = 0; b < BT; ++b) {
            float4 o = make_float4(v[b][0], v[b][1], v[b][2], v[b][3]);
            *reinterpret_cast<float4*>(
                out + ((size_t)(c * BATCH + b0 + b) * COUT) + tid * 4) = o;
        }
    }
}

extern "C" void kernel_launch(void* const* d_in, const int* in_sizes, int n_in,
                              void* d_out, int out_size, void* d_ws, size_t ws_size,
                              hipStream_t stream) {
    const float* x  = (const float*)d_in[0];
    const float* Wt = (const float*)d_in[1];
    float* out = (float*)d_out;
    capsule_routing_kernel<<<dim3(GRID), dim3(T), 0, stream>>>(x, Wt, out);
}

// Round 6
// 149.031 us; speedup vs baseline: 1.4991x; 1.3338x over previous
//
#include <hip/hip_runtime.h>
#include <stdint.h>

// CapsuleLayer dynamic routing, fused. Round 5 (resubmit after broker timeout):
//  - priors live in LDS (bf16, two u32 planes, 144 KB) -> register file
//    holds only the double-buffered W/x load pipeline (no spill)
//  - BT=4 batches/block, XCD-grouped c-major swizzle (W[c] L2-resident)
//  - iter-0 prior sum accumulated in fp32 during the prior phase
//
// x:  [B=256, N=1152, CIN=8] fp32 | W: [10, 1152, 8, 16] fp32
// out:[10, B, 1, 1, 16] fp32

constexpr int NCAPS  = 10;
constexpr int BATCH  = 256;
constexpr int NROUTE = 1152;
constexpr int CIN    = 8;
constexpr int COUT   = 16;
constexpr int T      = 512;                      // 8 waves
constexpr int NWAVES = T / 64;
constexpr int BT     = 4;                        // batches per block
constexpr int NSTEP  = NROUTE / (NWAVES * 16);   // 9
constexpr int BG     = BATCH / BT;               // 64
constexpr int GRID   = NCAPS * BG;               // 640 (=8*80, bijective swizzle)
constexpr int CPX    = GRID / 8;                 // 80 blocks per XCD

// Priors in LDS: plane g=0 holds o={4oq,4oq+1} packed, g=1 holds {4oq+2,4oq+3}.
// u32 index ((g*BT+b)*NROUTE + n)*4 + oq -> per-wave bank = lane%32 (2-way, free).
struct SMem {
    uint32_t pk[2][BT][NROUTE][4];   // 147456 B
    float red16[NWAVES][BT][COUT];   // 2048 B
    float sred[NWAVES][BT];          // 128 B
};
static_assert(sizeof(SMem) <= 160 * 1024, "LDS overflow");

__device__ inline uint32_t bf16rne(float f) {
    uint32_t u = __float_as_uint(f);
    return (u + 0x7fffu + ((u >> 16) & 1u)) >> 16;
}
__device__ inline uint32_t packbf(float a, float b) {
    return (bf16rne(a) << 16) | bf16rne(b);
}
__device__ inline float2 unpk(uint32_t u) {
    return make_float2(__uint_as_float(u & 0xffff0000u),
                       __uint_as_float(u << 16));
}
__device__ inline float fcomp(const float4& v, int j) {   // j compile-time
    return j == 0 ? v.x : j == 1 ? v.y : j == 2 ? v.z : v.w;
}

#define LOADW(KK, BUF) do {                                                      \
    const int n_ = (KK) * 128 + nbase;                                           \
    const float4* wp_ = reinterpret_cast<const float4*>(Wc + (size_t)n_ * 128) + oq; \
    _Pragma("unroll")                                                            \
    for (int i_ = 0; i_ < 8; ++i_) wreg[BUF][i_] = wp_[i_ * 4];                  \
} while (0)

#define LOADX(KK, BUF) do {                                                      \
    const int n_ = (KK) * 128 + nbase;                                           \
    _Pragma("unroll")                                                            \
    for (int b_ = 0; b_ < BT; ++b_) {                                            \
        const float4* xp_ = reinterpret_cast<const float4*>(                     \
            xbase + (size_t)b_ * (NROUTE * CIN) + (size_t)n_ * CIN);             \
        xreg[BUF][b_ * 2 + 0] = xp_[0];                                          \
        xreg[BUF][b_ * 2 + 1] = xp_[1];                                          \
    }                                                                            \
} while (0)

__global__ __launch_bounds__(T, 1)
void capsule_routing_kernel(const float* __restrict__ x,
                            const float* __restrict__ Wt,
                            float* __restrict__ out) {
    __shared__ SMem sm;
    const int phys    = blockIdx.x;
    const int logical = (phys & 7) * CPX + (phys >> 3);   // XCD-grouped, c-major
    const int c  = logical / BG;
    const int b0 = (logical % BG) * BT;
    const int tid  = threadIdx.x;
    const int lane = tid & 63;
    const int wid  = tid >> 6;
    const int nn   = lane >> 2;
    const int oq   = lane & 3;
    const int nbase = wid * 16 + nn;

    const float* Wc    = Wt + (size_t)c * NROUTE * (CIN * COUT);
    const float* xbase = x + (size_t)b0 * NROUTE * CIN;

    float part[BT][4], s[BT][4], v[BT][4];

    // ---- prior phase: 2-deep register pipeline, store bf16 pairs to LDS,
    //      accumulate the iter-0 (uniform-probs) sums in fp32 on the fly ---
    {
        float4 wreg[2][8];
        float4 xreg[2][8];
#pragma unroll
        for (int b = 0; b < BT; ++b)
#pragma unroll
            for (int j = 0; j < 4; ++j) part[b][j] = 0.f;

        LOADW(0, 0);
        LOADX(0, 0);
#pragma unroll
        for (int k = 0; k < NSTEP; ++k) {
            const int cur = k & 1;
            if (k + 1 < NSTEP) {
                if (cur == 0) { LOADW(k + 1, 1); LOADX(k + 1, 1); }
                else          { LOADW(k + 1, 0); LOADX(k + 1, 0); }
            }
            const int n = k * 128 + nbase;
#pragma unroll
            for (int b = 0; b < BT; ++b) {
                float a0 = 0.f, a1 = 0.f, a2 = 0.f, a3 = 0.f;
#pragma unroll
                for (int i = 0; i < 8; ++i) {
                    float4 w4 = wreg[cur][i];
                    float xi = fcomp(xreg[cur][b * 2 + (i >> 2)], i & 3);
                    a0 = fmaf(xi, w4.x, a0);
                    a1 = fmaf(xi, w4.y, a1);
                    a2 = fmaf(xi, w4.z, a2);
                    a3 = fmaf(xi, w4.w, a3);
                }
                part[b][0] += a0; part[b][1] += a1;
                part[b][2] += a2; part[b][3] += a3;
                sm.pk[0][b][n][oq] = packbf(a0, a1);
                sm.pk[1][b][n][oq] = packbf(a2, a3);
            }
        }
    }

    float bl[BT][NSTEP];

    // ---- iteration 0: probs uniform 1/N ----------------------------------
#pragma unroll
    for (int b = 0; b < BT; ++b)
#pragma unroll
        for (int j = 0; j < 4; ++j) {
            float t = part[b][j];
#pragma unroll
            for (int off = 4; off < 64; off <<= 1) t += __shfl_xor(t, off, 64);
            part[b][j] = t;
        }
    __syncthreads();
    if (lane < 4) {
#pragma unroll
        for (int b = 0; b < BT; ++b)
#pragma unroll
            for (int j = 0; j < 4; ++j) sm.red16[wid][b][lane * 4 + j] = part[b][j];
    }
    __syncthreads();
#pragma unroll
    for (int b = 0; b < BT; ++b) {
        float sn = 0.f;
#pragma unroll
        for (int j = 0; j < 4; ++j) {
            float acc = sm.red16[0][b][oq * 4 + j];
#pragma unroll
            for (int w = 1; w < NWAVES; ++w) acc += sm.red16[w][b][oq * 4 + j];
            s[b][j] = acc * (1.0f / NROUTE);
            sn += s[b][j] * s[b][j];
        }
        sn += __shfl_xor(sn, 1, 64);
        sn += __shfl_xor(sn, 2, 64);
        float scale = sn / ((1.f + sn) * sqrtf(sn));
#pragma unroll
        for (int j = 0; j < 4; ++j) v[b][j] = s[b][j] * scale;
    }
    // logits after iter 0 (priors re-read from LDS, own slice, no barrier)
#pragma unroll
    for (int b = 0; b < BT; ++b)
#pragma unroll
        for (int k = 0; k < NSTEP; ++k) {
            const int n = k * 128 + nbase;
            float2 u0 = unpk(sm.pk[0][b][n][oq]);
            float2 u1 = unpk(sm.pk[1][b][n][oq]);
            float d = u0.x * v[b][0] + u0.y * v[b][1] + u1.x * v[b][2] + u1.y * v[b][3];
            d += __shfl_xor(d, 1, 64);
            d += __shfl_xor(d, 2, 64);
            bl[b][k] = d;
        }

    // ---- iterations 1, 2 --------------------------------------------------
#pragma unroll
    for (int it = 1; it < 3; ++it) {
        // softmax max over n (oq duplicates harmless)
        float m[BT];
#pragma unroll
        for (int b = 0; b < BT; ++b) {
            float mm = bl[b][0];
#pragma unroll
            for (int k = 1; k < NSTEP; ++k) mm = fmaxf(mm, bl[b][k]);
#pragma unroll
            for (int off = 1; off < 64; off <<= 1) mm = fmaxf(mm, __shfl_xor(mm, off, 64));
            m[b] = mm;
        }
        __syncthreads();
        if (lane == 0) {
#pragma unroll
            for (int b = 0; b < BT; ++b) sm.sred[wid][b] = m[b];
        }
        __syncthreads();
#pragma unroll
        for (int b = 0; b < BT; ++b) {
            float mm = sm.sred[0][b];
#pragma unroll
            for (int w = 1; w < NWAVES; ++w) mm = fmaxf(mm, sm.sred[w][b]);
            m[b] = mm;
        }

        // fused pass: e = exp(bl-m) accumulated into Z and the 4 o-partials
        float es[BT];
#pragma unroll
        for (int b = 0; b < BT; ++b) {
            float ez = 0.f, a0 = 0, a1 = 0, a2 = 0, a3 = 0;
#pragma unroll
            for (int k = 0; k < NSTEP; ++k) {
                const int n = k * 128 + nbase;
                float ek = __expf(bl[b][k] - m[b]);
                ez += ek;
                float2 u0 = unpk(sm.pk[0][b][n][oq]);
                float2 u1 = unpk(sm.pk[1][b][n][oq]);
                a0 = fmaf(ek, u0.x, a0); a1 = fmaf(ek, u0.y, a1);
                a2 = fmaf(ek, u1.x, a2); a3 = fmaf(ek, u1.y, a3);
            }
#pragma unroll
            for (int off = 4; off < 64; off <<= 1) {
                a0 += __shfl_xor(a0, off, 64);
                a1 += __shfl_xor(a1, off, 64);
                a2 += __shfl_xor(a2, off, 64);
                a3 += __shfl_xor(a3, off, 64);
            }
            part[b][0] = a0; part[b][1] = a1; part[b][2] = a2; part[b][3] = a3;
#pragma unroll
            for (int off = 1; off < 64; off <<= 1) ez += __shfl_xor(ez, off, 64);
            es[b] = ez;
        }
        __syncthreads();
        if (lane < 4) {
#pragma unroll
            for (int b = 0; b < BT; ++b) {
#pragma unroll
                for (int j = 0; j < 4; ++j) sm.red16[wid][b][lane * 4 + j] = part[b][j];
                if (lane == 0) sm.sred[wid][b] = es[b];
            }
        }
        __syncthreads();
#pragma unroll
        for (int b = 0; b < BT; ++b) {
            float z = sm.sred[0][b];
#pragma unroll
            for (int w = 1; w < NWAVES; ++w) z += sm.sred[w][b];
            float invZ = 4.0f / z;             // each n counted 4x across quad
            float sn = 0.f;
#pragma unroll
            for (int j = 0; j < 4; ++j) {
                float acc = sm.red16[0][b][oq * 4 + j];
#pragma unroll
                for (int w = 1; w < NWAVES; ++w) acc += sm.red16[w][b][oq * 4 + j];
                s[b][j] = acc * invZ;
                sn += s[b][j] * s[b][j];
            }
            sn += __shfl_xor(sn, 1, 64);
            sn += __shfl_xor(sn, 2, 64);
            float scale = sn / ((1.f + sn) * sqrtf(sn));
#pragma unroll
            for (int j = 0; j < 4; ++j) v[b][j] = s[b][j] * scale;
        }

        if (it < 2) {
#pragma unroll
            for (int b = 0; b < BT; ++b)
#pragma unroll
                for (int k = 0; k < NSTEP; ++k) {
                    const int n = k * 128 + nbase;
                    float2 u0 = unpk(sm.pk[0][b][n][oq]);
                    float2 u1 = unpk(sm.pk[1][b][n][oq]);
                    float d = u0.x * v[b][0] + u0.y * v[b][1] + u1.x * v[b][2] + u1.y * v[b][3];
                    d += __shfl_xor(d, 1, 64);
                    d += __shfl_xor(d, 2, 64);
                    bl[b][k] += d;
                }
        }
    }

    // ---- write out[c, b0..b0+3, 0, 0, :] ---------------------------------
    if (tid < 4) {                         // wave 0, nn=0, lane==oq==tid
#pragma unroll
        for (int b = 0; b < BT; ++b) {
            float4 o = make_float4(v[b][0], v[b][1], v[b][2], v[b][3]);
            *reinterpret_cast<float4*>(
                out + ((size_t)(c * BATCH + b0 + b) * COUT) + tid * 4) = o;
        }
    }
}

extern "C" void kernel_launch(void* const* d_in, const int* in_sizes, int n_in,
                              void* d_out, int out_size, void* d_ws, size_t ws_size,
                              hipStream_t stream) {
    const float* x  = (const float*)d_in[0];
    const float* Wt = (const float*)d_in[1];
    float* out = (float*)d_out;
    capsule_routing_kernel<<<dim3(GRID), dim3(T), 0, stream>>>(x, Wt, out);
}

// Round 7
// 142.655 us; speedup vs baseline: 1.5661x; 1.0447x over previous
//
#include <hip/hip_runtime.h>
#include <stdint.h>

// CapsuleLayer dynamic routing, fused. Round 7:
//  - BT=2 -> LDS 75 KB -> 2 blocks/CU -> 16 waves/CU (4/SIMD) for latency
//    hiding; grid 1280 = 5*256 exactly
//  - priors in LDS (bf16 pairs), reg file holds only the load pipeline
//  - XCD-grouped c-major swizzle (W[c] L2-resident per XCD)
//
// x:  [B=256, N=1152, CIN=8] fp32 | W: [10, 1152, 8, 16] fp32
// out:[10, B, 1, 1, 16] fp32

constexpr int NCAPS  = 10;
constexpr int BATCH  = 256;
constexpr int NROUTE = 1152;
constexpr int CIN    = 8;
constexpr int COUT   = 16;
constexpr int T      = 512;                      // 8 waves
constexpr int NWAVES = T / 64;
constexpr int BT     = 2;                        // batches per block
constexpr int NSTEP  = NROUTE / (NWAVES * 16);   // 9
constexpr int BG     = BATCH / BT;               // 128
constexpr int GRID   = NCAPS * BG;               // 1280 (=8*160, bijective swizzle)
constexpr int CPX    = GRID / 8;                 // 160 blocks per XCD

// Priors in LDS: plane g=0 holds o={4oq,4oq+1} packed, g=1 holds {4oq+2,4oq+3}.
// u32 index ((g*BT+b)*NROUTE + n)*4 + oq -> per-wave bank = lane%32 (2-way, free).
struct SMem {
    uint32_t pk[2][BT][NROUTE][4];   // 73728 B
    float red16[NWAVES][BT][COUT];   // 1024 B
    float sred[NWAVES][BT];          // 64 B
};
static_assert(sizeof(SMem) <= 78 * 1024, "LDS too big for 2 blocks/CU");

__device__ inline uint32_t bf16rne(float f) {
    uint32_t u = __float_as_uint(f);
    return (u + 0x7fffu + ((u >> 16) & 1u)) >> 16;
}
__device__ inline uint32_t packbf(float a, float b) {
    return (bf16rne(a) << 16) | bf16rne(b);
}
__device__ inline float2 unpk(uint32_t u) {
    return make_float2(__uint_as_float(u & 0xffff0000u),
                       __uint_as_float(u << 16));
}
__device__ inline float fcomp(const float4& v, int j) {   // j compile-time
    return j == 0 ? v.x : j == 1 ? v.y : j == 2 ? v.z : v.w;
}

#define LOADW(KK, BUF) do {                                                      \
    const int n_ = (KK) * 128 + nbase;                                           \
    const float4* wp_ = reinterpret_cast<const float4*>(Wc + (size_t)n_ * 128) + oq; \
    _Pragma("unroll")                                                            \
    for (int i_ = 0; i_ < 8; ++i_) wreg[BUF][i_] = wp_[i_ * 4];                  \
} while (0)

#define LOADX(KK, BUF) do {                                                      \
    const int n_ = (KK) * 128 + nbase;                                           \
    _Pragma("unroll")                                                            \
    for (int b_ = 0; b_ < BT; ++b_) {                                            \
        const float4* xp_ = reinterpret_cast<const float4*>(                     \
            xbase + (size_t)b_ * (NROUTE * CIN) + (size_t)n_ * CIN);             \
        xreg[BUF][b_ * 2 + 0] = xp_[0];                                          \
        xreg[BUF][b_ * 2 + 1] = xp_[1];                                          \
    }                                                                            \
} while (0)

__global__ __launch_bounds__(T, 4)
void capsule_routing_kernel(const float* __restrict__ x,
                            const float* __restrict__ Wt,
                            float* __restrict__ out) {
    __shared__ SMem sm;
    const int phys    = blockIdx.x;
    const int logical = (phys & 7) * CPX + (phys >> 3);   // XCD-grouped, c-major
    const int c  = logical / BG;
    const int b0 = (logical % BG) * BT;
    const int tid  = threadIdx.x;
    const int lane = tid & 63;
    const int wid  = tid >> 6;
    const int nn   = lane >> 2;
    const int oq   = lane & 3;
    const int nbase = wid * 16 + nn;

    const float* Wc    = Wt + (size_t)c * NROUTE * (CIN * COUT);
    const float* xbase = x + (size_t)b0 * NROUTE * CIN;

    float part[BT][4], s[BT][4], v[BT][4];

    // ---- prior phase: 2-deep register pipeline, store bf16 pairs to LDS,
    //      accumulate the iter-0 (uniform-probs) sums in fp32 on the fly ---
    {
        float4 wreg[2][8];
        float4 xreg[2][BT * 2];
#pragma unroll
        for (int b = 0; b < BT; ++b)
#pragma unroll
            for (int j = 0; j < 4; ++j) part[b][j] = 0.f;

        LOADW(0, 0);
        LOADX(0, 0);
#pragma unroll
        for (int k = 0; k < NSTEP; ++k) {
            const int cur = k & 1;
            if (k + 1 < NSTEP) {
                if (cur == 0) { LOADW(k + 1, 1); LOADX(k + 1, 1); }
                else          { LOADW(k + 1, 0); LOADX(k + 1, 0); }
            }
            const int n = k * 128 + nbase;
#pragma unroll
            for (int b = 0; b < BT; ++b) {
                float a0 = 0.f, a1 = 0.f, a2 = 0.f, a3 = 0.f;
#pragma unroll
                for (int i = 0; i < 8; ++i) {
                    float4 w4 = wreg[cur][i];
                    float xi = fcomp(xreg[cur][b * 2 + (i >> 2)], i & 3);
                    a0 = fmaf(xi, w4.x, a0);
                    a1 = fmaf(xi, w4.y, a1);
                    a2 = fmaf(xi, w4.z, a2);
                    a3 = fmaf(xi, w4.w, a3);
                }
                part[b][0] += a0; part[b][1] += a1;
                part[b][2] += a2; part[b][3] += a3;
                sm.pk[0][b][n][oq] = packbf(a0, a1);
                sm.pk[1][b][n][oq] = packbf(a2, a3);
            }
        }
    }

    float bl[BT][NSTEP];

    // ---- iteration 0: probs uniform 1/N ----------------------------------
#pragma unroll
    for (int b = 0; b < BT; ++b)
#pragma unroll
        for (int j = 0; j < 4; ++j) {
            float t = part[b][j];
#pragma unroll
            for (int off = 4; off < 64; off <<= 1) t += __shfl_xor(t, off, 64);
            part[b][j] = t;
        }
    __syncthreads();
    if (lane < 4) {
#pragma unroll
        for (int b = 0; b < BT; ++b)
#pragma unroll
            for (int j = 0; j < 4; ++j) sm.red16[wid][b][lane * 4 + j] = part[b][j];
    }
    __syncthreads();
#pragma unroll
    for (int b = 0; b < BT; ++b) {
        float sn = 0.f;
#pragma unroll
        for (int j = 0; j < 4; ++j) {
            float acc = sm.red16[0][b][oq * 4 + j];
#pragma unroll
            for (int w = 1; w < NWAVES; ++w) acc += sm.red16[w][b][oq * 4 + j];
            s[b][j] = acc * (1.0f / NROUTE);
            sn += s[b][j] * s[b][j];
        }
        sn += __shfl_xor(sn, 1, 64);
        sn += __shfl_xor(sn, 2, 64);
        float scale = sn / ((1.f + sn) * sqrtf(sn));
#pragma unroll
        for (int j = 0; j < 4; ++j) v[b][j] = s[b][j] * scale;
    }
    // logits after iter 0 (priors re-read from LDS, own slice, no barrier)
#pragma unroll
    for (int b = 0; b < BT; ++b)
#pragma unroll
        for (int k = 0; k < NSTEP; ++k) {
            const int n = k * 128 + nbase;
            float2 u0 = unpk(sm.pk[0][b][n][oq]);
            float2 u1 = unpk(sm.pk[1][b][n][oq]);
            float d = u0.x * v[b][0] + u0.y * v[b][1] + u1.x * v[b][2] + u1.y * v[b][3];
            d += __shfl_xor(d, 1, 64);
            d += __shfl_xor(d, 2, 64);
            bl[b][k] = d;
        }

    // ---- iterations 1, 2 --------------------------------------------------
#pragma unroll
    for (int it = 1; it < 3; ++it) {
        // softmax max over n; bl identical across quad -> offs 4..32 suffice
        float m[BT];
#pragma unroll
        for (int b = 0; b < BT; ++b) {
            float mm = bl[b][0];
#pragma unroll
            for (int k = 1; k < NSTEP; ++k) mm = fmaxf(mm, bl[b][k]);
#pragma unroll
            for (int off = 4; off < 64; off <<= 1) mm = fmaxf(mm, __shfl_xor(mm, off, 64));
            m[b] = mm;
        }
        __syncthreads();
        if (lane == 0) {
#pragma unroll
            for (int b = 0; b < BT; ++b) sm.sred[wid][b] = m[b];
        }
        __syncthreads();
#pragma unroll
        for (int b = 0; b < BT; ++b) {
            float mm = sm.sred[0][b];
#pragma unroll
            for (int w = 1; w < NWAVES; ++w) mm = fmaxf(mm, sm.sred[w][b]);
            m[b] = mm;
        }

        // fused pass: e = exp(bl-m) accumulated into Z and the 4 o-partials
        float es[BT];
#pragma unroll
        for (int b = 0; b < BT; ++b) {
            float ez = 0.f, a0 = 0, a1 = 0, a2 = 0, a3 = 0;
#pragma unroll
            for (int k = 0; k < NSTEP; ++k) {
                const int n = k * 128 + nbase;
                float ek = __expf(bl[b][k] - m[b]);
                ez += ek;
                float2 u0 = unpk(sm.pk[0][b][n][oq]);
                float2 u1 = unpk(sm.pk[1][b][n][oq]);
                a0 = fmaf(ek, u0.x, a0); a1 = fmaf(ek, u0.y, a1);
                a2 = fmaf(ek, u1.x, a2); a3 = fmaf(ek, u1.y, a3);
            }
#pragma unroll
            for (int off = 4; off < 64; off <<= 1) {
                a0 += __shfl_xor(a0, off, 64);
                a1 += __shfl_xor(a1, off, 64);
                a2 += __shfl_xor(a2, off, 64);
                a3 += __shfl_xor(a3, off, 64);
            }
            part[b][0] = a0; part[b][1] = a1; part[b][2] = a2; part[b][3] = a3;
            // ez identical across quad lanes -> offs 4..32 give wave total
#pragma unroll
            for (int off = 4; off < 64; off <<= 1) ez += __shfl_xor(ez, off, 64);
            es[b] = ez;
        }
        __syncthreads();
        if (lane < 4) {
#pragma unroll
            for (int b = 0; b < BT; ++b) {
#pragma unroll
                for (int j = 0; j < 4; ++j) sm.red16[wid][b][lane * 4 + j] = part[b][j];
                if (lane == 0) sm.sred[wid][b] = es[b];
            }
        }
        __syncthreads();
#pragma unroll
        for (int b = 0; b < BT; ++b) {
            float z = sm.sred[0][b];
#pragma unroll
            for (int w = 1; w < NWAVES; ++w) z += sm.sred[w][b];
            float invZ = 1.0f / z;
            float sn = 0.f;
#pragma unroll
            for (int j = 0; j < 4; ++j) {
                float acc = sm.red16[0][b][oq * 4 + j];
#pragma unroll
                for (int w = 1; w < NWAVES; ++w) acc += sm.red16[w][b][oq * 4 + j];
                s[b][j] = acc * invZ;
                sn += s[b][j] * s[b][j];
            }
            sn += __shfl_xor(sn, 1, 64);
            sn += __shfl_xor(sn, 2, 64);
            float scale = sn / ((1.f + sn) * sqrtf(sn));
#pragma unroll
            for (int j = 0; j < 4; ++j) v[b][j] = s[b][j] * scale;
        }

        if (it < 2) {
#pragma unroll
            for (int b = 0; b < BT; ++b)
#pragma unroll
                for (int k = 0; k < NSTEP; ++k) {
                    const int n = k * 128 + nbase;
                    float2 u0 = unpk(sm.pk[0][b][n][oq]);
                    float2 u1 = unpk(sm.pk[1][b][n][oq]);
                    float d = u0.x * v[b][0] + u0.y * v[b][1] + u1.x * v[b][2] + u1.y * v[b][3];
                    d += __shfl_xor(d, 1, 64);
                    d += __shfl_xor(d, 2, 64);
                    bl[b][k] += d;
                }
        }
    }

    // ---- write out[c, b0..b0+1, 0, 0, :] ---------------------------------
    if (tid < 4) {                         // wave 0, nn=0, lane==oq==tid
#pragma unroll
        for (int b = 0; b < BT; ++b) {
            float4 o = make_float4(v[b][0], v[b][1], v[b][2], v[b][3]);
            *reinterpret_cast<float4*>(
                out + ((size_t)(c * BATCH + b0 + b) * COUT) + tid * 4) = o;
        }
    }
}

extern "C" void kernel_launch(void* const* d_in, const int* in_sizes, int n_in,
                              void* d_out, int out_size, void* d_ws, size_t ws_size,
                              hipStream_t stream) {
    const float* x  = (const float*)d_in[0];
    const float* Wt = (const float*)d_in[1];
    float* out = (float*)d_out;
    capsule_routing_kernel<<<dim3(GRID), dim3(T), 0, stream>>>(x, Wt, out);
}